// Round 10
// baseline (1855.303 us; speedup 1.0000x reference)
//
#include <hip/hip_runtime.h>

#define N_NODES 100000
#define N_EDGES 1600000
#define IN_C    128
#define HID     256
#define NLAYER  4

#define NBUCK 391     // ceil(N_NODES / 256) buckets, bucket = col >> 8
#define BCAP  8192    // padded per-bucket capacity in pairs buffer
#define EPB   4096    // edges per kb_scatter block
#define CAPL  6144    // per-bucket LDS srcl capacity in kb_build

#define GCH   128     // nodes per k_gat chunk
#define NCH   ((N_NODES + GCH - 1) / GCH)   // 782 chunks per slice

typedef __attribute__((ext_vector_type(8))) __bf16 bf16x8;
typedef __attribute__((ext_vector_type(4))) float  floatx4;
typedef __attribute__((ext_vector_type(2))) float  floatx2;

__device__ inline unsigned short f2b(float f) {
    unsigned u = __builtin_bit_cast(unsigned, f);
    return (unsigned short)((u + 0x7fffu + ((u >> 16) & 1u)) >> 16);
}
// packed accumulate: 8 bf16 (uint4) into 4 x floatx2 (lo,hi per word)
__device__ inline void acc8p(floatx2* a, uint4 v) {
    unsigned wds[4] = {v.x, v.y, v.z, v.w};
    #pragma unroll
    for (int k = 0; k < 4; ++k) {
        floatx2 t;
        t.x = __builtin_bit_cast(float, wds[k] << 16);
        t.y = __builtin_bit_cast(float, wds[k] & 0xffff0000u);
        a[k] += t;
    }
}

// ---------------- CSR build: bucket pipeline ----------------
__global__ void kb_zero(int* g, int m) {
    int i = blockIdx.x * blockDim.x + threadIdx.x;
    if (i < m) g[i] = 0;
}

__global__ __launch_bounds__(256) void kb_scatter(
        const int* __restrict__ row, const int* __restrict__ col,
        int* __restrict__ gfill, uint2* __restrict__ pairs, int e) {
    __shared__ uint2 ep[EPB];
    __shared__ int hist[NBUCK];
    __shared__ int lbase[NBUCK];
    const int tid  = threadIdx.x;
    const int base = blockIdx.x * EPB;
    for (int b = tid; b < NBUCK; b += 256) hist[b] = 0;
    __syncthreads();
    #pragma unroll
    for (int k = 0; k < EPB / 256; ++k) {
        int i = base + k * 256 + tid;
        uint2 pr = make_uint2(0xffffffffu, 0u);
        if (i < e) {
            pr.x = (unsigned)col[i];
            pr.y = (unsigned)row[i];
            atomicAdd(&hist[pr.x >> 8], 1);
        }
        ep[k * 256 + tid] = pr;
    }
    __syncthreads();
    for (int b = tid; b < NBUCK; b += 256) {
        int h = hist[b];
        lbase[b] = h ? atomicAdd(&gfill[b], h) : 0;
    }
    __syncthreads();
    for (int b = tid; b < NBUCK; b += 256) hist[b] = 0;
    __syncthreads();
    #pragma unroll
    for (int k = 0; k < EPB / 256; ++k) {
        uint2 pr = ep[k * 256 + tid];
        if (pr.x != 0xffffffffu) {
            int bk = pr.x >> 8;
            int p  = lbase[bk] + atomicAdd(&hist[bk], 1);
            if (p < BCAP) pairs[(size_t)bk * BCAP + p] = pr;
        }
    }
}

__global__ void kb_scan(const int* __restrict__ gfill, int* __restrict__ boff,
                        int* __restrict__ offs) {
    __shared__ int wsum[8];
    const int t = threadIdx.x, lane = t & 63, w = t >> 6;   // 512 threads
    int v = (t < NBUCK) ? gfill[t] : 0;
    int inc = v;
    #pragma unroll
    for (int o = 1; o < 64; o <<= 1) { int u = __shfl_up(inc, o); if (lane >= o) inc += u; }
    if (lane == 63) wsum[w] = inc;
    __syncthreads();
    if (t == 0) { int r = 0; for (int i = 0; i < 8; ++i) { int x = wsum[i]; wsum[i] = r; r += x; } }
    __syncthreads();
    int excl = wsum[w] + inc - v;
    if (t <= NBUCK) boff[t] = excl;
    if (t == 0) offs[N_NODES] = N_EDGES;
}

__global__ __launch_bounds__(256) void kb_build(
        const uint2* __restrict__ pairs, const int* __restrict__ gfill,
        const int* __restrict__ boff,
        int* __restrict__ offs, float* __restrict__ dis,
        int* __restrict__ srcl, int n) {
    __shared__ int lcnt[256];
    __shared__ int lstart[256];
    __shared__ int wsum[4];
    __shared__ int sl[CAPL];
    const int b = blockIdx.x;
    const int tid = threadIdx.x, lane = tid & 63, w = tid >> 6;
    int cnt = gfill[b]; if (cnt > CAPL) cnt = CAPL;
    const int base = boff[b];
    const uint2* bp = pairs + (size_t)b * BCAP;
    lcnt[tid] = 0;
    __syncthreads();
    for (int i = tid; i < cnt; i += 256)
        atomicAdd(&lcnt[bp[i].x & 255], 1);
    __syncthreads();
    int v = lcnt[tid];
    int inc = v;
    #pragma unroll
    for (int o = 1; o < 64; o <<= 1) { int u = __shfl_up(inc, o); if (lane >= o) inc += u; }
    if (lane == 63) wsum[w] = inc;
    __syncthreads();
    if (tid == 0) { int r = 0; for (int i = 0; i < 4; ++i) { int x = wsum[i]; wsum[i] = r; r += x; } }
    __syncthreads();
    int excl = wsum[w] + inc - v;
    lstart[tid] = excl;
    int node = (b << 8) + tid;
    if (node < n) {
        dis[node]  = rsqrtf((float)(v + 1));   // +1 self-loop
        offs[node] = base + excl;
    }
    __syncthreads();
    lcnt[tid] = 0;   // reuse as fill counters
    __syncthreads();
    for (int i = tid; i < cnt; i += 256) {
        uint2 pr = bp[i];
        int c = pr.x & 255;
        int q = lstart[c] + atomicAdd(&lcnt[c], 1);
        sl[q] = (int)pr.y;
    }
    __syncthreads();
    for (int i = tid; i < cnt; i += 256)
        srcl[base + i] = sl[i];
}

// ---------------- merged weight transpose+convert ----------------
__global__ void k_wt_all(const float* __restrict__ enc_w, const float* __restrict__ conv_w,
                         const float* __restrict__ w1,
                         unsigned short* __restrict__ enc_t, unsigned short* __restrict__ conv_t,
                         unsigned short* __restrict__ lin1_t) {
    int idx = blockIdx.x * blockDim.x + threadIdx.x;
    if (idx < IN_C * HID) {
        int k = idx / HID, n = idx % HID;
        enc_t[n * IN_C + k] = f2b(enc_w[idx]);
    } else if (idx < IN_C * HID + NLAYER * HID * HID) {
        int r = idx - IN_C * HID;
        int l = r / (HID * HID);
        int e = r % (HID * HID);
        int k = e / HID, n = e % HID;
        conv_t[(size_t)l * HID * HID + n * HID + k] = f2b(conv_w[r]);
    } else if (idx < IN_C * HID + NLAYER * HID * HID + HID * (HID / 2)) {
        int e = idx - (IN_C * HID + NLAYER * HID * HID);
        int k = e / (HID / 2), n = e % (HID / 2);
        lin1_t[n * HID + k] = f2b(w1[e]);
    }
}

// ---------------- MFMA GEMM: C[M,Nn] = A[M,K] @ Wt[Nn,K]^T ----------------
// MODE 0: enc  (A fp32, +bias,       store bf16 row-major)
// MODE 1: conv (A bf16, *scale[row], store bf16 SLICED [16][N_NODES][16])
template<int MODE>
__global__ __launch_bounds__(256) void k_mm(
        const void* __restrict__ Ain,
        const unsigned short* __restrict__ Wt,
        const float* __restrict__ bias, const float* __restrict__ scale,
        void* __restrict__ Cout, int M, int K, int Nn) {
    __shared__ unsigned short As[128 * 32];
    __shared__ unsigned short Bs[128 * 32];
    const int tid  = threadIdx.x;
    const int lane = tid & 63;
    const int w    = tid >> 6;
    const int bm   = blockIdx.x * 128;
    const int bn   = blockIdx.y * 128;

    const int i0 = tid, i1 = tid + 256;
    const int r0 = i0 >> 2, r1 = i1 >> 2;
    const int q0 = i0 & 3,  q1 = i1 & 3;
    const int a_off0 = min(bm + r0, M - 1) * K + q0 * 8;
    const int a_off1 = min(bm + r1, M - 1) * K + q1 * 8;
    const int b_off0 = (bn + r0) * K + q0 * 8;
    const int b_off1 = (bn + r1) * K + q1 * 8;

    floatx4 acc[4][4];
    #pragma unroll
    for (int i = 0; i < 4; ++i)
        #pragma unroll
        for (int j = 0; j < 4; ++j)
            acc[i][j] = (floatx4){0.f, 0.f, 0.f, 0.f};

    const int wm = (w & 1) * 64;
    const int wn = (w >> 1) * 64;
    const int fm = lane & 15;
    const int fq = (lane >> 4) * 8;

    const unsigned short* Ab = (const unsigned short*)Ain;
    const float*          Af = (const float*)Ain;

    uint4 ra0, ra1, rb0, rb1;
    auto loadA = [&](int koff, uint4& oa0, uint4& oa1) {
        if (MODE == 0) {
            float4 f0 = *(const float4*)(Af + a_off0 + koff);
            float4 f1 = *(const float4*)(Af + a_off0 + koff + 4);
            oa0.x = (unsigned)f2b(f0.x) | ((unsigned)f2b(f0.y) << 16);
            oa0.y = (unsigned)f2b(f0.z) | ((unsigned)f2b(f0.w) << 16);
            oa0.z = (unsigned)f2b(f1.x) | ((unsigned)f2b(f1.y) << 16);
            oa0.w = (unsigned)f2b(f1.z) | ((unsigned)f2b(f1.w) << 16);
            float4 g0 = *(const float4*)(Af + a_off1 + koff);
            float4 g1 = *(const float4*)(Af + a_off1 + koff + 4);
            oa1.x = (unsigned)f2b(g0.x) | ((unsigned)f2b(g0.y) << 16);
            oa1.y = (unsigned)f2b(g0.z) | ((unsigned)f2b(g0.w) << 16);
            oa1.z = (unsigned)f2b(g1.x) | ((unsigned)f2b(g1.y) << 16);
            oa1.w = (unsigned)f2b(g1.z) | ((unsigned)f2b(g1.w) << 16);
        } else {
            oa0 = *(const uint4*)(Ab + a_off0 + koff);
            oa1 = *(const uint4*)(Ab + a_off1 + koff);
        }
    };

    loadA(0, ra0, ra1);
    rb0 = *(const uint4*)(Wt + b_off0);
    rb1 = *(const uint4*)(Wt + b_off1);

    const int KT = K >> 5;
    for (int kt = 0; kt < KT; ++kt) {
        ((uint4*)As)[i0] = ra0; ((uint4*)As)[i1] = ra1;
        ((uint4*)Bs)[i0] = rb0; ((uint4*)Bs)[i1] = rb1;
        __syncthreads();
        if (kt + 1 < KT) {
            int k0 = (kt + 1) << 5;
            loadA(k0, ra0, ra1);
            rb0 = *(const uint4*)(Wt + b_off0 + k0);
            rb1 = *(const uint4*)(Wt + b_off1 + k0);
        }
        bf16x8 af[4], bfr[4];
        #pragma unroll
        for (int i = 0; i < 4; ++i)
            af[i] = *(const bf16x8*)(const void*)(As + (wm + i * 16 + fm) * 32 + fq);
        #pragma unroll
        for (int j = 0; j < 4; ++j)
            bfr[j] = *(const bf16x8*)(const void*)(Bs + (wn + j * 16 + fm) * 32 + fq);
        #pragma unroll
        for (int i = 0; i < 4; ++i)
            #pragma unroll
            for (int j = 0; j < 4; ++j)
                acc[i][j] = __builtin_amdgcn_mfma_f32_16x16x32_bf16(af[i], bfr[j], acc[i][j], 0, 0, 0);
        __syncthreads();
    }

    const int quad = lane >> 4;
    #pragma unroll
    for (int i = 0; i < 4; ++i) {
        #pragma unroll
        for (int r = 0; r < 4; ++r) {
            int row = bm + wm + i * 16 + quad * 4 + r;
            if (row >= M) continue;
            float sc = scale ? scale[row] : 1.f;
            #pragma unroll
            for (int j = 0; j < 4; ++j) {
                float v = acc[i][j][r];
                if (MODE == 0) {
                    int colg = bn + wn + j * 16 + fm;
                    v = (v + bias[colg]) * sc;
                    ((unsigned short*)Cout)[(size_t)row * Nn + colg] = f2b(v);
                } else {
                    v *= sc;
                    int region = ((bn + wn) >> 4) + j;   // feature slice 0..15
                    ((unsigned short*)Cout)[(size_t)region * N_NODES * 16 + (size_t)row * 16 + fm] = f2b(v);
                }
            }
        }
    }
}

// ---------------- fused head: out = relu(h@w1+b1)@w2 + b2 ----------------
__global__ __launch_bounds__(256) void k_head(
        const unsigned short* __restrict__ A,     // h bf16 [M,256]
        const unsigned short* __restrict__ Wt,    // lin1^T bf16 [128][256]
        const float* __restrict__ b1, const float* __restrict__ w2,
        const float* __restrict__ b2, float* __restrict__ out, int M) {
    const int K = 256;
    __shared__ unsigned short As[128 * 32];
    __shared__ unsigned short Bs[128 * 32];
    const int tid  = threadIdx.x;
    const int lane = tid & 63;
    const int w    = tid >> 6;
    const int bm   = blockIdx.x * 128;

    const int i0 = tid, i1 = tid + 256;
    const int r0 = i0 >> 2, r1 = i1 >> 2;
    const int q0 = i0 & 3,  q1 = i1 & 3;
    const int a_off0 = min(bm + r0, M - 1) * K + q0 * 8;
    const int a_off1 = min(bm + r1, M - 1) * K + q1 * 8;
    const int b_off0 = r0 * K + q0 * 8;
    const int b_off1 = r1 * K + q1 * 8;

    uint4 ra0, ra1, rb0, rb1;
    floatx4 acc[4][4];
    #pragma unroll
    for (int i = 0; i < 4; ++i)
        #pragma unroll
        for (int j = 0; j < 4; ++j)
            acc[i][j] = (floatx4){0.f, 0.f, 0.f, 0.f};

    const int wm = (w & 1) * 64;
    const int wn = (w >> 1) * 64;
    const int fm = lane & 15;
    const int fq = (lane >> 4) * 8;

    ra0 = *(const uint4*)(A + a_off0);
    ra1 = *(const uint4*)(A + a_off1);
    rb0 = *(const uint4*)(Wt + b_off0);
    rb1 = *(const uint4*)(Wt + b_off1);

    for (int kt = 0; kt < 8; ++kt) {
        ((uint4*)As)[i0] = ra0; ((uint4*)As)[i1] = ra1;
        ((uint4*)Bs)[i0] = rb0; ((uint4*)Bs)[i1] = rb1;
        __syncthreads();
        if (kt + 1 < 8) {
            int k0 = (kt + 1) << 5;
            ra0 = *(const uint4*)(A + a_off0 + k0);
            ra1 = *(const uint4*)(A + a_off1 + k0);
            rb0 = *(const uint4*)(Wt + b_off0 + k0);
            rb1 = *(const uint4*)(Wt + b_off1 + k0);
        }
        bf16x8 af[4], bfr[4];
        #pragma unroll
        for (int i = 0; i < 4; ++i)
            af[i] = *(const bf16x8*)(const void*)(As + (wm + i * 16 + fm) * 32 + fq);
        #pragma unroll
        for (int j = 0; j < 4; ++j)
            bfr[j] = *(const bf16x8*)(const void*)(Bs + (wn + j * 16 + fm) * 32 + fq);
        #pragma unroll
        for (int i = 0; i < 4; ++i)
            #pragma unroll
            for (int j = 0; j < 4; ++j)
                acc[i][j] = __builtin_amdgcn_mfma_f32_16x16x32_bf16(af[i], bfr[j], acc[i][j], 0, 0, 0);
        __syncthreads();
    }

    float* red = (float*)As;
    const int q = lane >> 4;
    float b1v[4], w2v[4];
    #pragma unroll
    for (int j = 0; j < 4; ++j) {
        int col = wn + j * 16 + fm;
        b1v[j] = b1[col]; w2v[j] = w2[col];
    }
    #pragma unroll
    for (int i = 0; i < 4; ++i) {
        #pragma unroll
        for (int r = 0; r < 4; ++r) {
            float s = 0.f;
            #pragma unroll
            for (int j = 0; j < 4; ++j)
                s += fmaxf(acc[i][j][r] + b1v[j], 0.f) * w2v[j];
            #pragma unroll
            for (int off = 1; off < 16; off <<= 1) s += __shfl_xor(s, off);
            if (fm == 0) {
                int m = wm + i * 16 + q * 4 + r;
                red[m * 2 + (wn >> 6)] = s;
            }
        }
    }
    __syncthreads();
    if (tid < 128) {
        int row = bm + tid;
        if (row < M) out[row] = red[tid * 2] + red[tid * 2 + 1] + b2[0];
    }
}

// ---------------- slice-gather v2: HW XCD affinity + work-stealing chunk queues ----------------
// slice = 2*xcd + phase; per-XCD L2 working set = one 3.2 MB slice table.
// 2 lanes per node (16 B each), serial edge walk, 8-deep unroll, dual acc chains.
__global__ __launch_bounds__(256) void k_gat(
        const unsigned short* __restrict__ Ts,   // sliced [16][N][16]
        const int* __restrict__ srcl, const int* __restrict__ offs,
        int* __restrict__ qctr,                  // 8 chunk counters (this dispatch's set)
        int phase,
        unsigned short* __restrict__ agg) {      // sliced [16][N][16]
    unsigned xcc;
    asm volatile("s_getreg_b32 %0, hwreg(HW_REG_XCC_ID)" : "=s"(xcc));
    xcc &= 7;
    __shared__ int curchunk;
    const int tid   = threadIdx.x;
    const int lane  = tid & 63;
    const int w     = tid >> 6;
    const int nodeL = lane >> 1;   // 0..31 within wave
    const int fpart = lane & 1;    // 16B half of the 32B slice row

    for (int soff = 0; soff < 8; ++soff) {
        int sx = (int)((xcc + soff) & 7);
        int slice = sx * 2 + phase;
        const unsigned short* T = Ts  + (size_t)slice * N_NODES * 16;
        unsigned short*       A = agg + (size_t)slice * N_NODES * 16;
        while (true) {
            if (tid == 0) curchunk = atomicAdd(&qctr[sx], 1);
            __syncthreads();
            int ch = curchunk;
            __syncthreads();
            if (ch >= NCH) break;
            int node = ch * GCH + w * 32 + nodeL;
            bool valid = node < N_NODES;
            floatx2 ac[4], cc[4];
            #pragma unroll
            for (int k = 0; k < 4; ++k) { ac[k] = (floatx2){0.f, 0.f}; cc[k] = (floatx2){0.f, 0.f}; }
            int p = 0, pe = 0;
            if (valid) {
                p  = offs[node];
                pe = offs[node + 1];
                uint4 sv = *(const uint4*)(T + (size_t)node * 16 + fpart * 8);
                acc8p(ac, sv);
            }
            for (; p + 8 <= pe; p += 8) {
                int s0 = srcl[p],     s1 = srcl[p + 1], s2 = srcl[p + 2], s3 = srcl[p + 3];
                int s4 = srcl[p + 4], s5 = srcl[p + 5], s6 = srcl[p + 6], s7 = srcl[p + 7];
                uint4 v0 = *(const uint4*)(T + (size_t)s0 * 16 + fpart * 8);
                uint4 v1 = *(const uint4*)(T + (size_t)s1 * 16 + fpart * 8);
                uint4 v2 = *(const uint4*)(T + (size_t)s2 * 16 + fpart * 8);
                uint4 v3 = *(const uint4*)(T + (size_t)s3 * 16 + fpart * 8);
                uint4 v4 = *(const uint4*)(T + (size_t)s4 * 16 + fpart * 8);
                uint4 v5 = *(const uint4*)(T + (size_t)s5 * 16 + fpart * 8);
                uint4 v6 = *(const uint4*)(T + (size_t)s6 * 16 + fpart * 8);
                uint4 v7 = *(const uint4*)(T + (size_t)s7 * 16 + fpart * 8);
                acc8p(ac, v0); acc8p(cc, v1); acc8p(ac, v2); acc8p(cc, v3);
                acc8p(ac, v4); acc8p(cc, v5); acc8p(ac, v6); acc8p(cc, v7);
            }
            for (; p < pe; ++p) {
                int s0 = srcl[p];
                uint4 v = *(const uint4*)(T + (size_t)s0 * 16 + fpart * 8);
                acc8p(ac, v);
            }
            if (valid) {
                uint4 st;
                floatx2 t0 = ac[0] + cc[0], t1 = ac[1] + cc[1];
                floatx2 t2 = ac[2] + cc[2], t3 = ac[3] + cc[3];
                st.x = (unsigned)f2b(t0.x) | ((unsigned)f2b(t0.y) << 16);
                st.y = (unsigned)f2b(t1.x) | ((unsigned)f2b(t1.y) << 16);
                st.z = (unsigned)f2b(t2.x) | ((unsigned)f2b(t2.y) << 16);
                st.w = (unsigned)f2b(t3.x) | ((unsigned)f2b(t3.y) << 16);
                *(uint4*)(A + (size_t)node * 16 + fpart * 8) = st;
            }
        }
    }
}

// ---------------- pass 2: h = relu(LN(agg*dis + bias)), sliced agg -> row-major hb ----------------
__global__ void k_fin(const unsigned short* __restrict__ agg,   // [16][N][16]
                      const float* __restrict__ dis,
                      const float* __restrict__ cb, const float* __restrict__ g,
                      const float* __restrict__ bt,
                      unsigned short* __restrict__ hout, int n) {
    int gtid = blockIdx.x * blockDim.x + threadIdx.x;
    int node = gtid >> 6;
    int lane = threadIdx.x & 63;
    if (node >= n) return;
    int s = lane >> 2;
    int o = (lane & 3) * 4;          // features f = lane*4 .. lane*4+3
    uint2 v = *(const uint2*)(agg + (size_t)s * N_NODES * 16 + (size_t)node * 16 + o);
    float dc = dis[node];
    float4 cbv = ((const float4*)cb)[lane];
    float h0 = fmaf(__builtin_bit_cast(float, v.x << 16),          dc, cbv.x);
    float h1 = fmaf(__builtin_bit_cast(float, v.x & 0xffff0000u),  dc, cbv.y);
    float h2 = fmaf(__builtin_bit_cast(float, v.y << 16),          dc, cbv.z);
    float h3 = fmaf(__builtin_bit_cast(float, v.y & 0xffff0000u),  dc, cbv.w);
    float sm = h0 + h1 + h2 + h3;
    float sq = h0 * h0 + h1 * h1 + h2 * h2 + h3 * h3;
    #pragma unroll
    for (int off = 1; off < 64; off <<= 1) { sm += __shfl_xor(sm, off); sq += __shfl_xor(sq, off); }
    float mu  = sm * (1.f / 256.f);
    float var = sq * (1.f / 256.f) - mu * mu;
    float inv = rsqrtf(var + 1e-5f);
    float4 gv = ((const float4*)g)[lane];
    float4 bv = ((const float4*)bt)[lane];
    ushort4 ot;
    ot.x = f2b(fmaxf(fmaf((h0 - mu) * inv, gv.x, bv.x), 0.f));
    ot.y = f2b(fmaxf(fmaf((h1 - mu) * inv, gv.y, bv.y), 0.f));
    ot.z = f2b(fmaxf(fmaf((h2 - mu) * inv, gv.z, bv.z), 0.f));
    ot.w = f2b(fmaxf(fmaf((h3 - mu) * inv, gv.w, bv.w), 0.f));
    *(ushort4*)(hout + (size_t)node * 256 + lane * 4) = ot;
}

extern "C" void kernel_launch(void* const* d_in, const int* in_sizes, int n_in,
                              void* d_out, int out_size, void* d_ws, size_t ws_size,
                              hipStream_t stream) {
    const float* x      = (const float*)d_in[0];
    const int*   ei     = (const int*)d_in[1];     // (2,E) int32
    const float* enc_w  = (const float*)d_in[2];
    const float* enc_b  = (const float*)d_in[3];
    const float* conv_w = (const float*)d_in[4];
    const float* conv_b = (const float*)d_in[5];
    const float* ln_g   = (const float*)d_in[6];
    const float* ln_b   = (const float*)d_in[7];
    const float* w1     = (const float*)d_in[8];
    const float* b1     = (const float*)d_in[9];
    const float* w2     = (const float*)d_in[10];
    const float* b2     = (const float*)d_in[11];
    float* out = (float*)d_out;

    char* ws = (char*)d_ws;
    size_t off = 0;
    auto alloc = [&](size_t bytes) -> void* {
        void* p = ws + off;
        off = (off + bytes + 255) & ~(size_t)255;
        return p;
    };
    int*   offs  = (int*)alloc((size_t)(N_NODES + 1) * 4);
    int*   srcl  = (int*)alloc((size_t)N_EDGES * 4);
    float* dis   = (float*)alloc((size_t)N_NODES * 4);
    int*   gfill = (int*)alloc((size_t)(NBUCK + NLAYER * 2 * 8) * 4);   // + gather queues
    int*   qctr  = gfill + NBUCK;                                       // 64 counters
    int*   boff  = (int*)alloc((size_t)(NBUCK + 1) * 4);
    unsigned short* hb = (unsigned short*)alloc((size_t)N_NODES * HID * 2);   // h, bf16 row-major
    unsigned short* hw = (unsigned short*)alloc((size_t)N_NODES * HID * 2);   // hw, bf16 SLICED
    // overlay: pairs (CSR build) then agg (conv layers) — lifetimes disjoint
    size_t pairs_bytes = (size_t)NBUCK * BCAP * 8;
    size_t agg_bytes   = (size_t)N_NODES * HID * 2;
    char* OV = (char*)alloc(pairs_bytes > agg_bytes ? pairs_bytes : agg_bytes);
    uint2*          pairs = (uint2*)OV;
    unsigned short* agg   = (unsigned short*)OV;
    unsigned short* enc_t  = (unsigned short*)alloc((size_t)IN_C * HID * 2);
    unsigned short* conv_t = (unsigned short*)alloc((size_t)NLAYER * HID * HID * 2);
    unsigned short* lin1_t = (unsigned short*)alloc((size_t)HID * (HID / 2) * 2);

    const int* row = ei;             // sources
    const int* col = ei + N_EDGES;   // targets

    // ---- CSR build (bucket pipeline) + zero the gather queues ----
    int nz = NBUCK + NLAYER * 2 * 8;
    kb_zero<<<(nz + 255) / 256, 256, 0, stream>>>(gfill, nz);
    kb_scatter<<<(N_EDGES + EPB - 1) / EPB, 256, 0, stream>>>(row, col, gfill, pairs, N_EDGES);
    kb_scan<<<1, 512, 0, stream>>>(gfill, boff, offs);
    kb_build<<<NBUCK, 256, 0, stream>>>(pairs, gfill, boff, offs, dis, srcl, N_NODES);

    // ---- weight conversions ----
    {
        int tot = IN_C * HID + NLAYER * HID * HID + HID * (HID / 2);
        k_wt_all<<<(tot + 255) / 256, 256, 0, stream>>>(enc_w, conv_w, w1, enc_t, conv_t, lin1_t);
    }

    // encoder: h0 = bf16(x @ enc_w + enc_b)
    {
        dim3 g((N_NODES + 127) / 128, HID / 128);
        k_mm<0><<<g, 256, 0, stream>>>(x, enc_t, enc_b, nullptr, hb, N_NODES, IN_C, HID);
    }

    for (int l = 0; l < NLAYER; ++l) {
        dim3 g((N_NODES + 127) / 128, HID / 128);
        // hw (sliced) = (h @ conv_w[l]) * dis[row]
        k_mm<1><<<g, 256, 0, stream>>>(hb, conv_t + (size_t)l * HID * HID, nullptr, dis,
                                       hw, N_NODES, HID, HID);
        k_gat<<<1024, 256, 0, stream>>>(hw, srcl, offs, qctr + (l * 2 + 0) * 8, 0, agg);
        k_gat<<<1024, 256, 0, stream>>>(hw, srcl, offs, qctr + (l * 2 + 1) * 8, 1, agg);
        k_fin<<<(N_NODES * 64) / 256, 256, 0, stream>>>(
            agg, dis, conv_b + l * HID, ln_g + l * HID, ln_b + l * HID, hb, N_NODES);
    }

    // fused head: out = relu(h@w1+b1)@w2 + b2
    k_head<<<(N_NODES + 127) / 128, 256, 0, stream>>>(hb, lin1_t, b1, w2, b2, out, N_NODES);
}

// Round 11
// 803.635 us; speedup vs baseline: 2.3086x; 2.3086x over previous
//
#include <hip/hip_runtime.h>

#define N_NODES 100000
#define N_EDGES 1600000
#define IN_C    128
#define HID     256
#define NLAYER  4

#define NBUCK 391     // ceil(N_NODES / 256) buckets, bucket = col >> 8
#define BCAP  8192    // padded per-bucket capacity in pairs buffer
#define EPB   4096    // edges per kb_scatter block
#define CAPL  6144    // per-bucket LDS srcl capacity in kb_build

typedef __attribute__((ext_vector_type(8))) __bf16 bf16x8;
typedef __attribute__((ext_vector_type(4))) float  floatx4;

__device__ inline unsigned short f2b(float f) {
    unsigned u = __builtin_bit_cast(unsigned, f);
    return (unsigned short)((u + 0x7fffu + ((u >> 16) & 1u)) >> 16);
}
// unpack+accumulate 8 bf16 (uint4) into fp32[8]
__device__ inline void acc8(float* a, uint4 v) {
    unsigned wds[4] = {v.x, v.y, v.z, v.w};
    #pragma unroll
    for (int k = 0; k < 4; ++k) {
        a[2*k]   += __builtin_bit_cast(float, wds[k] << 16);
        a[2*k+1] += __builtin_bit_cast(float, wds[k] & 0xffff0000u);
    }
}
// async global->LDS, 16 B per lane (lane-contiguous LDS dest required)
__device__ inline void gl16(const void* g, void* l) {
    __builtin_amdgcn_global_load_lds(
        (const __attribute__((address_space(1))) unsigned int*)g,
        (__attribute__((address_space(3))) unsigned int*)l, 16, 0, 0);
}

// ---------------- CSR build: bucket pipeline ----------------
__global__ __launch_bounds__(256) void kb_scatter(
        const int* __restrict__ row, const int* __restrict__ col,
        int* __restrict__ gfill, uint2* __restrict__ pairs, int e) {
    __shared__ uint2 ep[EPB];
    __shared__ int hist[NBUCK];
    __shared__ int lbase[NBUCK];
    const int tid  = threadIdx.x;
    const int base = blockIdx.x * EPB;
    for (int b = tid; b < NBUCK; b += 256) hist[b] = 0;
    __syncthreads();
    #pragma unroll
    for (int k = 0; k < EPB / 256; ++k) {
        int i = base + k * 256 + tid;
        uint2 pr = make_uint2(0xffffffffu, 0u);
        if (i < e) {
            pr.x = (unsigned)col[i];
            pr.y = (unsigned)row[i];
            atomicAdd(&hist[pr.x >> 8], 1);
        }
        ep[k * 256 + tid] = pr;
    }
    __syncthreads();
    for (int b = tid; b < NBUCK; b += 256) {
        int h = hist[b];
        lbase[b] = h ? atomicAdd(&gfill[b], h) : 0;
    }
    __syncthreads();
    for (int b = tid; b < NBUCK; b += 256) hist[b] = 0;
    __syncthreads();
    #pragma unroll
    for (int k = 0; k < EPB / 256; ++k) {
        uint2 pr = ep[k * 256 + tid];
        if (pr.x != 0xffffffffu) {
            int bk = pr.x >> 8;
            int p  = lbase[bk] + atomicAdd(&hist[bk], 1);
            if (p < BCAP) pairs[(size_t)bk * BCAP + p] = pr;
        }
    }
}

__global__ void kb_scan(const int* __restrict__ gfill, int* __restrict__ boff,
                        int* __restrict__ offs) {
    __shared__ int wsum[8];
    const int t = threadIdx.x, lane = t & 63, w = t >> 6;   // 512 threads
    int v = (t < NBUCK) ? gfill[t] : 0;
    int inc = v;
    #pragma unroll
    for (int o = 1; o < 64; o <<= 1) { int u = __shfl_up(inc, o); if (lane >= o) inc += u; }
    if (lane == 63) wsum[w] = inc;
    __syncthreads();
    if (t == 0) { int r = 0; for (int i = 0; i < 8; ++i) { int x = wsum[i]; wsum[i] = r; r += x; } }
    __syncthreads();
    int excl = wsum[w] + inc - v;
    if (t <= NBUCK) boff[t] = excl;
    if (t == 0) offs[N_NODES] = N_EDGES;
}

__global__ __launch_bounds__(256) void kb_build(
        const uint2* __restrict__ pairs, const int* __restrict__ gfill,
        const int* __restrict__ boff,
        int* __restrict__ offs, float* __restrict__ dis,
        int* __restrict__ srcl, int n) {
    __shared__ int lcnt[256];
    __shared__ int lstart[256];
    __shared__ int wsum[4];
    __shared__ int sl[CAPL];
    const int b = blockIdx.x;
    const int tid = threadIdx.x, lane = tid & 63, w = tid >> 6;
    int cnt = gfill[b]; if (cnt > CAPL) cnt = CAPL;
    const int base = boff[b];
    const uint2* bp = pairs + (size_t)b * BCAP;
    lcnt[tid] = 0;
    __syncthreads();
    for (int i = tid; i < cnt; i += 256)
        atomicAdd(&lcnt[bp[i].x & 255], 1);
    __syncthreads();
    int v = lcnt[tid];
    int inc = v;
    #pragma unroll
    for (int o = 1; o < 64; o <<= 1) { int u = __shfl_up(inc, o); if (lane >= o) inc += u; }
    if (lane == 63) wsum[w] = inc;
    __syncthreads();
    if (tid == 0) { int r = 0; for (int i = 0; i < 4; ++i) { int x = wsum[i]; wsum[i] = r; r += x; } }
    __syncthreads();
    int excl = wsum[w] + inc - v;
    lstart[tid] = excl;
    int node = (b << 8) + tid;
    if (node < n) {
        dis[node]  = rsqrtf((float)(v + 1));   // +1 self-loop
        offs[node] = base + excl;
    }
    __syncthreads();
    lcnt[tid] = 0;   // reuse as fill counters
    __syncthreads();
    for (int i = tid; i < cnt; i += 256) {
        uint2 pr = bp[i];
        int c = pr.x & 255;
        int q = lstart[c] + atomicAdd(&lcnt[c], 1);
        sl[q] = (int)pr.y;
    }
    __syncthreads();
    for (int i = tid; i < cnt; i += 256)
        srcl[base + i] = sl[i];
}

// ---------------- merged: zero gfill + weight transpose/convert ----------------
__global__ void k_wtz(const float* __restrict__ enc_w, const float* __restrict__ conv_w,
                      const float* __restrict__ w1,
                      unsigned short* __restrict__ enc_t, unsigned short* __restrict__ conv_t,
                      unsigned short* __restrict__ lin1_t, int* __restrict__ gfill) {
    int idx = blockIdx.x * blockDim.x + threadIdx.x;
    if (idx < NBUCK) gfill[idx] = 0;
    if (idx < IN_C * HID) {
        int k = idx / HID, n = idx % HID;
        enc_t[n * IN_C + k] = f2b(enc_w[idx]);
    } else if (idx < IN_C * HID + NLAYER * HID * HID) {
        int r = idx - IN_C * HID;
        int l = r / (HID * HID);
        int e = r % (HID * HID);
        int k = e / HID, n = e % HID;
        conv_t[(size_t)l * HID * HID + n * HID + k] = f2b(conv_w[r]);
    } else if (idx < IN_C * HID + NLAYER * HID * HID + HID * (HID / 2)) {
        int e = idx - (IN_C * HID + NLAYER * HID * HID);
        int k = e / (HID / 2), n = e % (HID / 2);
        lin1_t[n * HID + k] = f2b(w1[e]);
    }
}

// ---------------- encoder GEMM: hb = bf16(x(fp32) @ enc_t^T + bias) ----------------
__global__ __launch_bounds__(256) void k_mme(
        const float* __restrict__ Af,
        const unsigned short* __restrict__ Wt,     // [256][128]
        const float* __restrict__ bias,
        unsigned short* __restrict__ Cout, int M) {
    const int K = IN_C, Nn = HID;
    __shared__ unsigned short As[128 * 32];
    __shared__ unsigned short Bs[128 * 32];
    const int tid  = threadIdx.x;
    const int lane = tid & 63;
    const int w    = tid >> 6;
    const int bm   = blockIdx.x * 128;
    const int bn   = blockIdx.y * 128;

    const int i0 = tid, i1 = tid + 256;
    const int r0 = i0 >> 2, r1 = i1 >> 2;
    const int q0 = i0 & 3,  q1 = i1 & 3;
    const int a_off0 = min(bm + r0, M - 1) * K + q0 * 8;
    const int a_off1 = min(bm + r1, M - 1) * K + q1 * 8;
    const int b_off0 = (bn + r0) * K + q0 * 8;
    const int b_off1 = (bn + r1) * K + q1 * 8;

    floatx4 acc[4][4];
    #pragma unroll
    for (int i = 0; i < 4; ++i)
        #pragma unroll
        for (int j = 0; j < 4; ++j)
            acc[i][j] = (floatx4){0.f, 0.f, 0.f, 0.f};

    const int wm = (w & 1) * 64;
    const int wn = (w >> 1) * 64;
    const int fm = lane & 15;
    const int fq = (lane >> 4) * 8;

    uint4 ra0, ra1, rb0, rb1;
    auto loadA = [&](int koff, uint4& oa0, uint4& oa1) {
        float4 f0 = *(const float4*)(Af + a_off0 + koff);
        float4 f1 = *(const float4*)(Af + a_off0 + koff + 4);
        oa0.x = (unsigned)f2b(f0.x) | ((unsigned)f2b(f0.y) << 16);
        oa0.y = (unsigned)f2b(f0.z) | ((unsigned)f2b(f0.w) << 16);
        oa0.z = (unsigned)f2b(f1.x) | ((unsigned)f2b(f1.y) << 16);
        oa0.w = (unsigned)f2b(f1.z) | ((unsigned)f2b(f1.w) << 16);
        float4 g0 = *(const float4*)(Af + a_off1 + koff);
        float4 g1 = *(const float4*)(Af + a_off1 + koff + 4);
        oa1.x = (unsigned)f2b(g0.x) | ((unsigned)f2b(g0.y) << 16);
        oa1.y = (unsigned)f2b(g0.z) | ((unsigned)f2b(g0.w) << 16);
        oa1.z = (unsigned)f2b(g1.x) | ((unsigned)f2b(g1.y) << 16);
        oa1.w = (unsigned)f2b(g1.z) | ((unsigned)f2b(g1.w) << 16);
    };

    loadA(0, ra0, ra1);
    rb0 = *(const uint4*)(Wt + b_off0);
    rb1 = *(const uint4*)(Wt + b_off1);

    const int KT = K >> 5;   // 4
    for (int kt = 0; kt < KT; ++kt) {
        ((uint4*)As)[i0] = ra0; ((uint4*)As)[i1] = ra1;
        ((uint4*)Bs)[i0] = rb0; ((uint4*)Bs)[i1] = rb1;
        __syncthreads();
        if (kt + 1 < KT) {
            int k0 = (kt + 1) << 5;
            loadA(k0, ra0, ra1);
            rb0 = *(const uint4*)(Wt + b_off0 + k0);
            rb1 = *(const uint4*)(Wt + b_off1 + k0);
        }
        bf16x8 af[4], bfr[4];
        #pragma unroll
        for (int i = 0; i < 4; ++i)
            af[i] = *(const bf16x8*)(const void*)(As + (wm + i * 16 + fm) * 32 + fq);
        #pragma unroll
        for (int j = 0; j < 4; ++j)
            bfr[j] = *(const bf16x8*)(const void*)(Bs + (wn + j * 16 + fm) * 32 + fq);
        #pragma unroll
        for (int i = 0; i < 4; ++i)
            #pragma unroll
            for (int j = 0; j < 4; ++j)
                acc[i][j] = __builtin_amdgcn_mfma_f32_16x16x32_bf16(af[i], bfr[j], acc[i][j], 0, 0, 0);
        __syncthreads();
    }

    const int quad = lane >> 4;
    #pragma unroll
    for (int i = 0; i < 4; ++i) {
        #pragma unroll
        for (int r = 0; r < 4; ++r) {
            int row = bm + wm + i * 16 + quad * 4 + r;
            if (row >= M) continue;
            #pragma unroll
            for (int j = 0; j < 4; ++j) {
                int colg = bn + wn + j * 16 + fm;
                float v = acc[i][j][r] + bias[colg];
                Cout[(size_t)row * Nn + colg] = f2b(v);
            }
        }
    }
}

// ---------------- conv GEMM (bf16): hw = bf16((h @ W) * scale[row]) ----------------
// single-buffer LDS staging via async global_load_lds width=16 (m97 pattern)
__global__ __launch_bounds__(256) void k_mmc(
        const unsigned short* __restrict__ A,      // [M][256] bf16
        const unsigned short* __restrict__ Wt,     // [256][256] bf16
        const float* __restrict__ scale,
        unsigned short* __restrict__ Cout, int M) {
    const int K = HID, Nn = HID;
    __shared__ unsigned short As[128 * 32];
    __shared__ unsigned short Bs[128 * 32];
    const int tid  = threadIdx.x;
    const int lane = tid & 63;
    const int w    = tid >> 6;
    const int bm   = blockIdx.x * 128;
    const int bn   = blockIdx.y * 128;

    const int i0 = tid, i1 = tid + 256;
    const int r0 = i0 >> 2, r1 = i1 >> 2;
    const int q0 = i0 & 3,  q1 = i1 & 3;
    const int a_off0 = min(bm + r0, M - 1) * K + q0 * 8;
    const int a_off1 = min(bm + r1, M - 1) * K + q1 * 8;
    const int b_off0 = (bn + r0) * K + q0 * 8;
    const int b_off1 = (bn + r1) * K + q1 * 8;

    floatx4 acc[4][4];
    #pragma unroll
    for (int i = 0; i < 4; ++i)
        #pragma unroll
        for (int j = 0; j < 4; ++j)
            acc[i][j] = (floatx4){0.f, 0.f, 0.f, 0.f};

    const int wm = (w & 1) * 64;
    const int wn = (w >> 1) * 64;
    const int fm = lane & 15;
    const int fq = (lane >> 4) * 8;

    for (int kt = 0; kt < 8; ++kt) {
        int k0 = kt << 5;
        gl16(A  + a_off0 + k0, As + (size_t)i0 * 8);
        gl16(A  + a_off1 + k0, As + (size_t)i1 * 8);
        gl16(Wt + b_off0 + k0, Bs + (size_t)i0 * 8);
        gl16(Wt + b_off1 + k0, Bs + (size_t)i1 * 8);
        __syncthreads();
        bf16x8 af[4], bfr[4];
        #pragma unroll
        for (int i = 0; i < 4; ++i)
            af[i] = *(const bf16x8*)(const void*)(As + (wm + i * 16 + fm) * 32 + fq);
        #pragma unroll
        for (int j = 0; j < 4; ++j)
            bfr[j] = *(const bf16x8*)(const void*)(Bs + (wn + j * 16 + fm) * 32 + fq);
        #pragma unroll
        for (int i = 0; i < 4; ++i)
            #pragma unroll
            for (int j = 0; j < 4; ++j)
                acc[i][j] = __builtin_amdgcn_mfma_f32_16x16x32_bf16(af[i], bfr[j], acc[i][j], 0, 0, 0);
        __syncthreads();
    }

    const int quad = lane >> 4;
    #pragma unroll
    for (int i = 0; i < 4; ++i) {
        #pragma unroll
        for (int r = 0; r < 4; ++r) {
            int row = bm + wm + i * 16 + quad * 4 + r;
            if (row >= M) continue;
            float sc = scale[row];
            #pragma unroll
            for (int j = 0; j < 4; ++j) {
                int colg = bn + wn + j * 16 + fm;
                Cout[(size_t)row * Nn + colg] = f2b(acc[i][j][r] * sc);
            }
        }
    }
}

// ---------------- fused head: out = relu(h@w1+b1)@w2 + b2 ----------------
__global__ __launch_bounds__(256) void k_head(
        const unsigned short* __restrict__ A,     // h bf16 [M,256]
        const unsigned short* __restrict__ Wt,    // lin1^T bf16 [128][256]
        const float* __restrict__ b1, const float* __restrict__ w2,
        const float* __restrict__ b2, float* __restrict__ out, int M) {
    const int K = 256;
    __shared__ unsigned short As[128 * 32];
    __shared__ unsigned short Bs[128 * 32];
    const int tid  = threadIdx.x;
    const int lane = tid & 63;
    const int w    = tid >> 6;
    const int bm   = blockIdx.x * 128;

    const int i0 = tid, i1 = tid + 256;
    const int r0 = i0 >> 2, r1 = i1 >> 2;
    const int q0 = i0 & 3,  q1 = i1 & 3;
    const int a_off0 = min(bm + r0, M - 1) * K + q0 * 8;
    const int a_off1 = min(bm + r1, M - 1) * K + q1 * 8;
    const int b_off0 = r0 * K + q0 * 8;
    const int b_off1 = r1 * K + q1 * 8;

    floatx4 acc[4][4];
    #pragma unroll
    for (int i = 0; i < 4; ++i)
        #pragma unroll
        for (int j = 0; j < 4; ++j)
            acc[i][j] = (floatx4){0.f, 0.f, 0.f, 0.f};

    const int wm = (w & 1) * 64;
    const int wn = (w >> 1) * 64;
    const int fm = lane & 15;
    const int fq = (lane >> 4) * 8;

    for (int kt = 0; kt < 8; ++kt) {
        int k0 = kt << 5;
        gl16(A  + a_off0 + k0, As + (size_t)i0 * 8);
        gl16(A  + a_off1 + k0, As + (size_t)i1 * 8);
        gl16(Wt + b_off0 + k0, Bs + (size_t)i0 * 8);
        gl16(Wt + b_off1 + k0, Bs + (size_t)i1 * 8);
        __syncthreads();
        bf16x8 af[4], bfr[4];
        #pragma unroll
        for (int i = 0; i < 4; ++i)
            af[i] = *(const bf16x8*)(const void*)(As + (wm + i * 16 + fm) * 32 + fq);
        #pragma unroll
        for (int j = 0; j < 4; ++j)
            bfr[j] = *(const bf16x8*)(const void*)(Bs + (wn + j * 16 + fm) * 32 + fq);
        #pragma unroll
        for (int i = 0; i < 4; ++i)
            #pragma unroll
            for (int j = 0; j < 4; ++j)
                acc[i][j] = __builtin_amdgcn_mfma_f32_16x16x32_bf16(af[i], bfr[j], acc[i][j], 0, 0, 0);
        __syncthreads();
    }

    // epilogue: relu(acc + b1) dot w2, reduce into out
    float* red = (float*)As;   // 256 floats, safe after final barrier
    const int q = lane >> 4;
    float b1v[4], w2v[4];
    #pragma unroll
    for (int j = 0; j < 4; ++j) {
        int col = wn + j * 16 + fm;
        b1v[j] = b1[col]; w2v[j] = w2[col];
    }
    #pragma unroll
    for (int i = 0; i < 4; ++i) {
        #pragma unroll
        for (int r = 0; r < 4; ++r) {
            float s = 0.f;
            #pragma unroll
            for (int j = 0; j < 4; ++j)
                s += fmaxf(acc[i][j][r] + b1v[j], 0.f) * w2v[j];
            #pragma unroll
            for (int off = 1; off < 16; off <<= 1) s += __shfl_xor(s, off);
            if (fm == 0) {
                int m = wm + i * 16 + q * 4 + r;
                red[m * 2 + (wn >> 6)] = s;
            }
        }
    }
    __syncthreads();
    if (tid < 128) {
        int row = bm + tid;
        if (row < M) out[row] = red[tid * 2] + red[tid * 2 + 1] + b2[0];
    }
}

// ---------------- aggregation + bias + LayerNorm + ReLU, one wave per node ----------------
// 2 edges per wave (lanes 0-31 / 32-63), 16B/lane; scalar index loads; 8-edge unroll (R7 variant)
__global__ void k_agg(const unsigned short* __restrict__ hw, const int* __restrict__ srcl,
                      const int* __restrict__ offs, const float* __restrict__ dis,
                      const float* __restrict__ cb, const float* __restrict__ g,
                      const float* __restrict__ bt, unsigned short* __restrict__ hout, int n) {
    int gtid = blockIdx.x * blockDim.x + threadIdx.x;
    int node = __builtin_amdgcn_readfirstlane(gtid >> 6);   // grid sized so node < n always
    int lane = threadIdx.x & 63;
    const int half = lane >> 5;
    const int sub  = lane & 31;
    const uint4* T = (const uint4*)hw;    // row = 32 x uint4 (512 B)

    float a[8] = {0,0,0,0,0,0,0,0};
    float c[8] = {0,0,0,0,0,0,0,0};
    if (half == 0) {
        uint4 v = T[(size_t)node * 32 + sub];   // self-loop (pre-scaled by dis[src])
        acc8(a, v);
    }
    int p = offs[node], pe = offs[node + 1];
    for (; p + 7 < pe; p += 8) {
        int s0 = srcl[p],     s1 = srcl[p + 1], s2 = srcl[p + 2], s3 = srcl[p + 3];
        int s4 = srcl[p + 4], s5 = srcl[p + 5], s6 = srcl[p + 6], s7 = srcl[p + 7];
        int ea = half ? s1 : s0;
        int eb = half ? s3 : s2;
        int ec = half ? s5 : s4;
        int ed = half ? s7 : s6;
        uint4 va = T[(size_t)ea * 32 + sub];
        uint4 vb = T[(size_t)eb * 32 + sub];
        uint4 vc = T[(size_t)ec * 32 + sub];
        uint4 vd = T[(size_t)ed * 32 + sub];
        acc8(a, va);
        acc8(c, vb);
        acc8(a, vc);
        acc8(c, vd);
    }
    for (; p + 1 < pe; p += 2) {
        int s0 = srcl[p], s1 = srcl[p + 1];
        int ea = half ? s1 : s0;
        uint4 v = T[(size_t)ea * 32 + sub];
        acc8(a, v);
    }
    if (p < pe && half == 0) {
        int s0 = srcl[p];
        uint4 v = T[(size_t)s0 * 32 + sub];
        acc8(a, v);
    }
    #pragma unroll
    for (int j = 0; j < 8; ++j) {
        a[j] += c[j];
        a[j] += __shfl_xor(a[j], 32);   // combine edge-parity halves
    }
    // lanes 0-31 (and duplicated 32-63) now hold the full aggregate; features f = sub*8+j
    float dc = dis[node];
    const float4* cb4 = (const float4*)cb;
    const float4* g4  = (const float4*)g;
    const float4* bt4 = (const float4*)bt;
    float4 cba = cb4[sub * 2], cbb = cb4[sub * 2 + 1];
    float h[8];
    h[0] = fmaf(a[0], dc, cba.x); h[1] = fmaf(a[1], dc, cba.y);
    h[2] = fmaf(a[2], dc, cba.z); h[3] = fmaf(a[3], dc, cba.w);
    h[4] = fmaf(a[4], dc, cbb.x); h[5] = fmaf(a[5], dc, cbb.y);
    h[6] = fmaf(a[6], dc, cbb.z); h[7] = fmaf(a[7], dc, cbb.w);
    float s = 0.f, sq = 0.f;
    #pragma unroll
    for (int j = 0; j < 8; ++j) { s += h[j]; sq += h[j] * h[j]; }
    #pragma unroll
    for (int off = 1; off < 32; off <<= 1) { s += __shfl_xor(s, off); sq += __shfl_xor(sq, off); }
    float mu  = s * (1.f / 256.f);
    float var = sq * (1.f / 256.f) - mu * mu;
    float inv = rsqrtf(var + 1e-5f);
    if (half == 0) {
        float4 ga = g4[sub * 2], gb = g4[sub * 2 + 1];
        float4 ba = bt4[sub * 2], bb = bt4[sub * 2 + 1];
        float gv[8] = {ga.x, ga.y, ga.z, ga.w, gb.x, gb.y, gb.z, gb.w};
        float bv[8] = {ba.x, ba.y, ba.z, ba.w, bb.x, bb.y, bb.z, bb.w};
        unsigned short o[8];
        #pragma unroll
        for (int j = 0; j < 8; ++j)
            o[j] = f2b(fmaxf(fmaf((h[j] - mu) * inv, gv[j], bv[j]), 0.f));
        uint4 st;
        st.x = (unsigned)o[0] | ((unsigned)o[1] << 16);
        st.y = (unsigned)o[2] | ((unsigned)o[3] << 16);
        st.z = (unsigned)o[4] | ((unsigned)o[5] << 16);
        st.w = (unsigned)o[6] | ((unsigned)o[7] << 16);
        ((uint4*)hout)[(size_t)node * 32 + sub] = st;
    }
}

extern "C" void kernel_launch(void* const* d_in, const int* in_sizes, int n_in,
                              void* d_out, int out_size, void* d_ws, size_t ws_size,
                              hipStream_t stream) {
    const float* x      = (const float*)d_in[0];
    const int*   ei     = (const int*)d_in[1];     // (2,E) int32
    const float* enc_w  = (const float*)d_in[2];
    const float* enc_b  = (const float*)d_in[3];
    const float* conv_w = (const float*)d_in[4];
    const float* conv_b = (const float*)d_in[5];
    const float* ln_g   = (const float*)d_in[6];
    const float* ln_b   = (const float*)d_in[7];
    const float* w1     = (const float*)d_in[8];
    const float* b1     = (const float*)d_in[9];
    const float* w2     = (const float*)d_in[10];
    const float* b2     = (const float*)d_in[11];
    float* out = (float*)d_out;

    char* ws = (char*)d_ws;
    size_t off = 0;
    auto alloc = [&](size_t bytes) -> void* {
        void* p = ws + off;
        off = (off + bytes + 255) & ~(size_t)255;
        return p;
    };
    int*   offs  = (int*)alloc((size_t)(N_NODES + 1) * 4);
    int*   srcl  = (int*)alloc((size_t)N_EDGES * 4);
    float* dis   = (float*)alloc((size_t)N_NODES * 4);
    int*   gfill = (int*)alloc((size_t)NBUCK * 4);
    int*   boff  = (int*)alloc((size_t)(NBUCK + 1) * 4);
    unsigned short* hb = (unsigned short*)alloc((size_t)N_NODES * HID * 2);   // h, bf16
    unsigned short* hw = (unsigned short*)alloc((size_t)N_NODES * HID * 2);   // hw, bf16
    uint2* pairs = (uint2*)alloc((size_t)NBUCK * BCAP * 8);
    unsigned short* enc_t  = (unsigned short*)alloc((size_t)IN_C * HID * 2);
    unsigned short* conv_t = (unsigned short*)alloc((size_t)NLAYER * HID * HID * 2);
    unsigned short* lin1_t = (unsigned short*)alloc((size_t)HID * (HID / 2) * 2);

    const int* row = ei;             // sources
    const int* col = ei + N_EDGES;   // targets

    // ---- weight conversion + gfill zero (merged), then CSR bucket pipeline ----
    {
        int tot = IN_C * HID + NLAYER * HID * HID + HID * (HID / 2);
        k_wtz<<<(tot + 255) / 256, 256, 0, stream>>>(enc_w, conv_w, w1,
                                                     enc_t, conv_t, lin1_t, gfill);
    }
    kb_scatter<<<(N_EDGES + EPB - 1) / EPB, 256, 0, stream>>>(row, col, gfill, pairs, N_EDGES);
    kb_scan<<<1, 512, 0, stream>>>(gfill, boff, offs);
    kb_build<<<NBUCK, 256, 0, stream>>>(pairs, gfill, boff, offs, dis, srcl, N_NODES);

    // encoder: h0 = bf16(x @ enc_w + enc_b)  -- unscaled; conv GEMM applies dis[row]
    {
        dim3 g((N_NODES + 127) / 128, HID / 128);
        k_mme<<<g, 256, 0, stream>>>(x, enc_t, enc_b, hb, N_NODES);
    }

    for (int l = 0; l < NLAYER; ++l) {
        dim3 g((N_NODES + 127) / 128, HID / 128);
        // hw = (h @ conv_w[l]) * dis[row]  (source pre-scale for the gather)
        k_mmc<<<g, 256, 0, stream>>>(hb, conv_t + (size_t)l * HID * HID, dis, hw, N_NODES);
        k_agg<<<(N_NODES * 64 + 255) / 256, 256, 0, stream>>>(
            hw, srcl, offs, dis, conv_b + l * HID, ln_g + l * HID, ln_b + l * HID, hb, N_NODES);
    }

    // fused head: out = relu(h@w1+b1)@w2 + b2
    k_head<<<(N_NODES + 127) / 128, 256, 0, stream>>>(hb, lin1_t, b1, w2, b2, out, N_NODES);
}